// Round 3
// baseline (441.924 us; speedup 1.0000x reference)
//
#include <hip/hip_runtime.h>
#include <hip/hip_bf16.h>

// Problem constants: B=8, NE=2048, D=1024, HEADS=16, hd=64
#define D_DIM 1024
#define M_TOT 16384      // B*NE
#define N_TOT 3072       // 2*D (qk) + D (v)
#define NQK   2048
#define QKV_SZ 16777216  // 8*16*2048*64

typedef __attribute__((ext_vector_type(8))) __bf16 bf16x8;
typedef __attribute__((ext_vector_type(4))) float floatx4;

__device__ __forceinline__ unsigned short f2bf(float f) {
  unsigned int u = __float_as_uint(f);
  u += 0x7FFFu + ((u >> 16) & 1u);   // round-to-nearest-even
  return (unsigned short)(u >> 16);
}

__device__ __forceinline__ void gl2lds16(const void* g, void* l) {
  // 16B per lane, dest = wave-uniform base + lane*16
  __builtin_amdgcn_global_load_lds(
      (const __attribute__((address_space(1))) void*)g,
      (__attribute__((address_space(3))) void*)l, 16, 0, 0);
}

// ---------------- 1) LayerNorm + cast to bf16 ----------------
__global__ __launch_bounds__(256) void ln_kernel(
    const float* __restrict__ inp, const float* __restrict__ gamma,
    const float* __restrict__ beta, unsigned short* __restrict__ X) {
  const int row = blockIdx.x;
  const int t = threadIdx.x;
  const float* rp = inp + (size_t)row * D_DIM;
  float4 v = *(const float4*)(rp + t * 4);
  float s  = v.x + v.y + v.z + v.w;
  float s2 = v.x * v.x + v.y * v.y + v.z * v.z + v.w * v.w;
#pragma unroll
  for (int o = 1; o < 64; o <<= 1) {
    s  += __shfl_xor(s, o);
    s2 += __shfl_xor(s2, o);
  }
  __shared__ float ws[8];
  const int w = t >> 6, l = t & 63;
  if (l == 0) { ws[w] = s; ws[4 + w] = s2; }
  __syncthreads();
  s  = ws[0] + ws[1] + ws[2] + ws[3];
  s2 = ws[4] + ws[5] + ws[6] + ws[7];
  const float mu = s * (1.0f / D_DIM);
  const float var = s2 * (1.0f / D_DIM) - mu * mu;
  const float rstd = rsqrtf(var + 1e-5f);
  float4 g = *(const float4*)(gamma + t * 4);
  float4 b = *(const float4*)(beta + t * 4);
  ushort4 o;
  o.x = f2bf((v.x - mu) * rstd * g.x + b.x);
  o.y = f2bf((v.y - mu) * rstd * g.y + b.y);
  o.z = f2bf((v.z - mu) * rstd * g.z + b.z);
  o.w = f2bf((v.w - mu) * rstd * g.w + b.w);
  *(ushort4*)(X + (size_t)row * D_DIM + t * 4) = o;
}

// ---------------- 2) Weight transpose + cast: Wt[n][k] = W[k][n] ----------------
__global__ __launch_bounds__(256) void wt_kernel(
    const float* __restrict__ Wqk, const float* __restrict__ Wv,
    unsigned short* __restrict__ Wt) {
  __shared__ float tile[64][65];
  const int n0 = blockIdx.x * 64;
  const int k0 = blockIdx.y * 64;
  const float* src;
  int ldn, nc0;
  if (n0 < NQK) { src = Wqk; ldn = NQK; nc0 = n0; }
  else          { src = Wv;  ldn = D_DIM; nc0 = n0 - NQK; }
  const int t = threadIdx.x;
  const int r = t >> 4;            // 0..15
  const int c4 = (t & 15) << 2;    // 0..60
#pragma unroll
  for (int p = 0; p < 4; ++p) {
    int kk = p * 16 + r;
    float4 vv = *(const float4*)(src + (size_t)(k0 + kk) * ldn + nc0 + c4);
    tile[kk][c4 + 0] = vv.x;
    tile[kk][c4 + 1] = vv.y;
    tile[kk][c4 + 2] = vv.z;
    tile[kk][c4 + 3] = vv.w;
  }
  __syncthreads();
#pragma unroll
  for (int p = 0; p < 4; ++p) {
    int nn = p * 16 + r;
    ushort4 o;
    o.x = f2bf(tile[c4 + 0][nn]);
    o.y = f2bf(tile[c4 + 1][nn]);
    o.z = f2bf(tile[c4 + 2][nn]);
    o.w = f2bf(tile[c4 + 3][nn]);
    *(ushort4*)(Wt + (size_t)(n0 + nn) * D_DIM + k0 + c4) = o;
  }
}

// ---------------- 3) GEMM + bias + qkv scatter ----------------
// C[M=16384, N=3072] = X(bf16) @ Wt^T(bf16) ; tile 128x128, BK=64, 4 waves (2x2)
__global__ __launch_bounds__(256) void gemm_kernel(
    const unsigned short* __restrict__ X,    // [16384][1024] bf16
    const unsigned short* __restrict__ Wt,   // [3072][1024] bf16
    const float* __restrict__ bqk, const float* __restrict__ bv,
    float* __restrict__ out) {
  __shared__ __align__(16) unsigned short As[128 * 64];
  __shared__ __align__(16) unsigned short Bs[128 * 64];

  const int bm = blockIdx.x / 24;
  const int bn = blockIdx.x % 24;
  const int m0 = bm * 128;
  const int n0 = bn * 128;
  const int tid = threadIdx.x;
  const int w = tid >> 6, l = tid & 63;
  const int wm = w >> 1, wn = w & 1;     // 2x2 wave grid, each 64x64
  const int lr = l & 15;                 // A-row / B-col select within 16
  const int lg = l >> 4;                 // k-group 0..3

  // staging: each lane 16B (8 bf16); one call-line = 4 waves x 8 rows = 32 rows.
  // 4 calls per operand cover all 128 rows of the tile.
  const int srow = w * 8 + (l >> 3);     // 0..31 across the block
  const int scol = (l & 7) * 8;
  const unsigned short* gA = X  + (size_t)(m0 + srow) * D_DIM + scol;
  const unsigned short* gB = Wt + (size_t)(n0 + srow) * D_DIM + scol;
  char* lA = (char*)As + w * 1024;       // wave-uniform byte base
  char* lB = (char*)Bs + w * 1024;

  floatx4 acc[4][4];
#pragma unroll
  for (int i = 0; i < 4; ++i)
#pragma unroll
    for (int j = 0; j < 4; ++j) acc[i][j] = (floatx4){0.f, 0.f, 0.f, 0.f};

  for (int kt = 0; kt < D_DIM / 64; ++kt) {
    const int ko = kt * 64;
#pragma unroll
    for (int p = 0; p < 4; ++p) {
      gl2lds16(gA + (size_t)(p * 32) * D_DIM + ko, lA + p * 4096);
      gl2lds16(gB + (size_t)(p * 32) * D_DIM + ko, lB + p * 4096);
    }
    __syncthreads();   // drains vmcnt before barrier
#pragma unroll
    for (int ks = 0; ks < 2; ++ks) {
      bf16x8 af[4], bf[4];
#pragma unroll
      for (int mi = 0; mi < 4; ++mi)
        af[mi] = *(const bf16x8*)(As + (wm * 64 + mi * 16 + lr) * 64 + ks * 32 + lg * 8);
#pragma unroll
      for (int ni = 0; ni < 4; ++ni)
        bf[ni] = *(const bf16x8*)(Bs + (wn * 64 + ni * 16 + lr) * 64 + ks * 32 + lg * 8);
#pragma unroll
      for (int mi = 0; mi < 4; ++mi)
#pragma unroll
        for (int ni = 0; ni < 4; ++ni)
          acc[mi][ni] = __builtin_amdgcn_mfma_f32_16x16x32_bf16(af[mi], bf[ni], acc[mi][ni], 0, 0, 0);
    }
    __syncthreads();
  }

  // Epilogue: C/D layout col = l&15, row = (l>>4)*4 + reg
  const size_t OQ = 0, OK = QKV_SZ, OV = 2 * (size_t)QKV_SZ;
  const int mb = m0 + wm * 64;
  const int bb = mb >> 11;               // batch index (uniform per block)
#pragma unroll
  for (int ni = 0; ni < 4; ++ni) {
    const int col = wn * 64 + ni * 16 + lr;
    const int ng = n0 + col;
#pragma unroll
    for (int mi = 0; mi < 4; ++mi) {
      const int mrow = mb + mi * 16 + lg * 4;   // global m of reg 0
      const int ne = mrow & 2047;
      floatx4 a = acc[mi][ni];
      if (ng < NQK) {
        const float bias = bqk[ng];
        const int h = ng >> 7;
        const int d = (ng & 127) >> 1;
        if ((ng & 1) == 0) {
          // q[b][h][ne][d], ne stride = 64
          float* p = out + OQ + (((size_t)(bb * 16 + h) * 2048 + ne) * 64 + d);
          p[0]   = a[0] + bias;
          p[64]  = a[1] + bias;
          p[128] = a[2] + bias;
          p[192] = a[3] + bias;
        } else {
          // k[b][h][d][ne], ne contiguous -> float4
          float* p = out + OK + ((size_t)(bb * 16 + h) * 64 + d) * 2048 + ne;
          float4 kv = make_float4(a[0] + bias, a[1] + bias, a[2] + bias, a[3] + bias);
          *(float4*)p = kv;
        }
      } else {
        const int nn = ng - NQK;
        const float bias = bv[nn];
        const int h = nn >> 6;
        const int d = nn & 63;
        float* p = out + OV + (((size_t)(bb * 16 + h) * 2048 + ne) * 64 + d);
        p[0]   = a[0] + bias;
        p[64]  = a[1] + bias;
        p[128] = a[2] + bias;
        p[192] = a[3] + bias;
      }
    }
  }
}

extern "C" void kernel_launch(void* const* d_in, const int* in_sizes, int n_in,
                              void* d_out, int out_size, void* d_ws, size_t ws_size,
                              hipStream_t stream) {
  const float* inp   = (const float*)d_in[0];
  const float* gamma = (const float*)d_in[1];
  const float* beta  = (const float*)d_in[2];
  const float* Wqk   = (const float*)d_in[3];
  const float* bqk   = (const float*)d_in[4];
  const float* Wv    = (const float*)d_in[5];
  const float* bv    = (const float*)d_in[6];
  float* out = (float*)d_out;

  unsigned short* X  = (unsigned short*)d_ws;             // 16384*1024 bf16 = 32 MB
  unsigned short* Wt = X + (size_t)M_TOT * D_DIM;         // 3072*1024 bf16  = 6 MB

  ln_kernel<<<M_TOT, 256, 0, stream>>>(inp, gamma, beta, X);
  wt_kernel<<<dim3(N_TOT / 64, D_DIM / 64), 256, 0, stream>>>(Wqk, Wv, Wt);
  gemm_kernel<<<(M_TOT / 128) * (N_TOT / 128), 256, 0, stream>>>(X, Wt, bqk, bv, out);
}

// Round 4
// 414.193 us; speedup vs baseline: 1.0670x; 1.0670x over previous
//
#include <hip/hip_runtime.h>
#include <hip/hip_bf16.h>

// Problem constants: B=8, NE=2048, D=1024, HEADS=16, hd=64
#define D_DIM 1024
#define M_TOT 16384      // B*NE
#define N_TOT 3072       // 2*D (qk) + D (v)
#define NQK   2048
#define QKV_SZ 16777216  // 8*16*2048*64

typedef __attribute__((ext_vector_type(8))) __bf16 bf16x8;
typedef __attribute__((ext_vector_type(4))) float floatx4;

__device__ __forceinline__ unsigned short f2bf(float f) {
  unsigned int u = __float_as_uint(f);
  u += 0x7FFFu + ((u >> 16) & 1u);   // round-to-nearest-even
  return (unsigned short)(u >> 16);
}

__device__ __forceinline__ void gl2lds16(const void* g, void* l) {
  // 16B per lane, dest = wave-uniform base + lane*16
  __builtin_amdgcn_global_load_lds(
      (const __attribute__((address_space(1))) void*)g,
      (__attribute__((address_space(3))) void*)l, 16, 0, 0);
}

// ---------------- 1) LayerNorm + cast to bf16 ----------------
__global__ __launch_bounds__(256) void ln_kernel(
    const float* __restrict__ inp, const float* __restrict__ gamma,
    const float* __restrict__ beta, unsigned short* __restrict__ X) {
  const int row = blockIdx.x;
  const int t = threadIdx.x;
  const float* rp = inp + (size_t)row * D_DIM;
  float4 v = *(const float4*)(rp + t * 4);
  float s  = v.x + v.y + v.z + v.w;
  float s2 = v.x * v.x + v.y * v.y + v.z * v.z + v.w * v.w;
#pragma unroll
  for (int o = 1; o < 64; o <<= 1) {
    s  += __shfl_xor(s, o);
    s2 += __shfl_xor(s2, o);
  }
  __shared__ float ws[8];
  const int w = t >> 6, l = t & 63;
  if (l == 0) { ws[w] = s; ws[4 + w] = s2; }
  __syncthreads();
  s  = ws[0] + ws[1] + ws[2] + ws[3];
  s2 = ws[4] + ws[5] + ws[6] + ws[7];
  const float mu = s * (1.0f / D_DIM);
  const float var = s2 * (1.0f / D_DIM) - mu * mu;
  const float rstd = rsqrtf(var + 1e-5f);
  float4 g = *(const float4*)(gamma + t * 4);
  float4 b = *(const float4*)(beta + t * 4);
  ushort4 o;
  o.x = f2bf((v.x - mu) * rstd * g.x + b.x);
  o.y = f2bf((v.y - mu) * rstd * g.y + b.y);
  o.z = f2bf((v.z - mu) * rstd * g.z + b.z);
  o.w = f2bf((v.w - mu) * rstd * g.w + b.w);
  *(ushort4*)(X + (size_t)row * D_DIM + t * 4) = o;
}

// ---------------- 2) Weight transpose + cast: Wt[n][k] = W[k][n] ----------------
__global__ __launch_bounds__(256) void wt_kernel(
    const float* __restrict__ Wqk, const float* __restrict__ Wv,
    unsigned short* __restrict__ Wt) {
  __shared__ float tile[64][65];
  const int n0 = blockIdx.x * 64;
  const int k0 = blockIdx.y * 64;
  const float* src;
  int ldn, nc0;
  if (n0 < NQK) { src = Wqk; ldn = NQK; nc0 = n0; }
  else          { src = Wv;  ldn = D_DIM; nc0 = n0 - NQK; }
  const int t = threadIdx.x;
  const int r = t >> 4;            // 0..15
  const int c4 = (t & 15) << 2;    // 0..60
#pragma unroll
  for (int p = 0; p < 4; ++p) {
    int kk = p * 16 + r;
    float4 vv = *(const float4*)(src + (size_t)(k0 + kk) * ldn + nc0 + c4);
    tile[kk][c4 + 0] = vv.x;
    tile[kk][c4 + 1] = vv.y;
    tile[kk][c4 + 2] = vv.z;
    tile[kk][c4 + 3] = vv.w;
  }
  __syncthreads();
#pragma unroll
  for (int p = 0; p < 4; ++p) {
    int nn = p * 16 + r;
    ushort4 o;
    o.x = f2bf(tile[c4 + 0][nn]);
    o.y = f2bf(tile[c4 + 1][nn]);
    o.z = f2bf(tile[c4 + 2][nn]);
    o.w = f2bf(tile[c4 + 3][nn]);
    *(ushort4*)(Wt + (size_t)(n0 + nn) * D_DIM + k0 + c4) = o;
  }
}

// ---------------- 3) GEMM + bias + qkv scatter ----------------
// C[16384,3072] = X @ Wt^T ; 128x128 tile, BK=64, 4 waves (2x2)
// 2-phase double-buffered staging (T3-min) + LDS-bounced coalesced epilogue.
__global__ __launch_bounds__(256) void gemm_kernel(
    const unsigned short* __restrict__ X,    // [16384][1024] bf16
    const unsigned short* __restrict__ Wt,   // [3072][1024] bf16
    const float* __restrict__ bqk, const float* __restrict__ bv,
    float* __restrict__ out) {
  // smem map: [0,16K) A0 | [16K,32K) A1 | [32K,48K) B0 | [48K,64K) B1
  // epilogue aliases [0,33280) as float C[128][65]
  __shared__ __align__(16) unsigned char smem[65536];

  const int bm = blockIdx.x / 24;
  const int bn = blockIdx.x % 24;
  const int m0 = bm * 128;
  const int n0 = bn * 128;
  const int tid = threadIdx.x;
  const int w = tid >> 6, l = tid & 63;
  const int wm = w >> 1, wn = w & 1;     // 2x2 wave grid, each 64x64
  const int lr = l & 15;
  const int lg = l >> 4;

  // staging: lane 16B; one call = 4 waves x 8 rows = 32 rows; 4 calls/operand
  const int srow = w * 8 + (l >> 3);     // 0..31
  const int scol = (l & 7) * 8;
  const unsigned short* gA = X  + (size_t)(m0 + srow) * D_DIM + scol;
  const unsigned short* gB = Wt + (size_t)(n0 + srow) * D_DIM + scol;
  const int lbase = w * 1024;            // wave-uniform byte base

  floatx4 acc[4][4];
#pragma unroll
  for (int i = 0; i < 4; ++i)
#pragma unroll
    for (int j = 0; j < 4; ++j) acc[i][j] = (floatx4){0.f, 0.f, 0.f, 0.f};

#define STAGE(buf, kt)                                                        \
  {                                                                           \
    const int ko_ = (kt) * 64;                                                \
    unsigned char* la_ = smem + (buf) * 16384 + lbase;                        \
    unsigned char* lb_ = smem + 32768 + (buf) * 16384 + lbase;                \
    _Pragma("unroll")                                                         \
    for (int p = 0; p < 4; ++p) {                                             \
      gl2lds16(gA + (size_t)(p * 32) * D_DIM + ko_, la_ + p * 4096);          \
      gl2lds16(gB + (size_t)(p * 32) * D_DIM + ko_, lb_ + p * 4096);          \
    }                                                                         \
  }

#define COMPUTE(buf)                                                          \
  {                                                                           \
    const unsigned short* As_ = (const unsigned short*)(smem + (buf) * 16384);\
    const unsigned short* Bs_ = (const unsigned short*)(smem + 32768 + (buf) * 16384); \
    _Pragma("unroll")                                                         \
    for (int ks = 0; ks < 2; ++ks) {                                          \
      bf16x8 af[4], bf[4];                                                    \
      _Pragma("unroll")                                                       \
      for (int mi = 0; mi < 4; ++mi)                                          \
        af[mi] = *(const bf16x8*)(As_ + (wm * 64 + mi * 16 + lr) * 64 + ks * 32 + lg * 8); \
      _Pragma("unroll")                                                       \
      for (int ni = 0; ni < 4; ++ni)                                          \
        bf[ni] = *(const bf16x8*)(Bs_ + (wn * 64 + ni * 16 + lr) * 64 + ks * 32 + lg * 8); \
      _Pragma("unroll")                                                       \
      for (int mi = 0; mi < 4; ++mi)                                          \
        _Pragma("unroll")                                                     \
        for (int ni = 0; ni < 4; ++ni)                                        \
          acc[mi][ni] = __builtin_amdgcn_mfma_f32_16x16x32_bf16(af[mi], bf[ni], acc[mi][ni], 0, 0, 0); \
    }                                                                         \
  }

  // ---- 2-phase pipelined K-loop (16 K-steps of 64) ----
  STAGE(0, 0);
  __syncthreads();
  int cur = 0;
#pragma unroll 1
  for (int kt = 0; kt < 15; ++kt) {
    STAGE(cur ^ 1, kt + 1);   // prefetch next tile; latency hides under MFMA
    COMPUTE(cur);
    __syncthreads();          // drains vmcnt(0): prefetch landed; buffers safe
    cur ^= 1;
  }
  COMPUTE(cur);

  // ---- epilogue: bounce C through LDS, coalesced float4 stores ----
  const size_t OQ = 0, OK = QKV_SZ, OV = 2 * (size_t)QKV_SZ;
  const int bb = m0 >> 11;           // batch (m-tile never crosses b boundary)
  const int mloc = m0 & 2047;        // ne base of this tile
  float* Cf = (float*)smem;          // [128][65] f32 = 33280 B

#pragma unroll 1
  for (int pass = 0; pass < 2; ++pass) {
    __syncthreads();                 // LDS free / previous pass consumed
    if (wn == pass) {
#pragma unroll
      for (int ni = 0; ni < 4; ++ni) {
        const int cl = ni * 16 + lr;                 // 0..63 within pass
        const int ng = n0 + pass * 64 + cl;
        const float bias = (ng < NQK) ? bqk[ng] : bv[ng - NQK];
#pragma unroll
        for (int mi = 0; mi < 4; ++mi) {
          const int r0 = wm * 64 + mi * 16 + lg * 4;
#pragma unroll
          for (int j = 0; j < 4; ++j)
            Cf[(r0 + j) * 65 + cl] = acc[mi][ni][j] + bias;
        }
      }
    }
    __syncthreads();
    if (n0 < NQK) {
      const int h = n0 >> 7;         // one head per 128-wide qk tile
      {
        // q: 128 rows x 32 d (even local cols). thread: row=tid>>1, 16 d.
        const int row = tid >> 1, doff = (tid & 1) * 16;
        const int d0 = pass * 32 + doff;
        float* qp = out + OQ + (((size_t)(bb * 16 + h) * 2048 + mloc + row) * 64) + d0;
        float vbuf[16];
#pragma unroll
        for (int i = 0; i < 16; ++i)
          vbuf[i] = Cf[row * 65 + 2 * (doff + i)];
#pragma unroll
        for (int i4 = 0; i4 < 4; ++i4)
          *(float4*)(qp + i4 * 4) = make_float4(vbuf[i4*4], vbuf[i4*4+1], vbuf[i4*4+2], vbuf[i4*4+3]);
      }
      {
        // k: 32 d x 128 ne (odd local cols). thread: d=pass*32+(tid>>3), 16 ne.
        const int dl = tid >> 3;               // local 0..31
        const int neo = (tid & 7) * 16;
        const int d = pass * 32 + dl;
        float* kp = out + OK + (((size_t)(bb * 16 + h) * 64 + d) * 2048) + mloc + neo;
        float vbuf[16];
#pragma unroll
        for (int i = 0; i < 16; ++i)
          vbuf[i] = Cf[(neo + i) * 65 + 2 * dl + 1];
#pragma unroll
        for (int i4 = 0; i4 < 4; ++i4)
          *(float4*)(kp + i4 * 4) = make_float4(vbuf[i4*4], vbuf[i4*4+1], vbuf[i4*4+2], vbuf[i4*4+3]);
      }
    } else {
      // v: one head per 64-col pass, d = local col. thread: row=tid>>1, 32 d.
      const int vbase = (n0 - NQK) + pass * 64;
      const int h = vbase >> 6;
      const int row = tid >> 1, off = (tid & 1) * 32;
      float* vp = out + OV + (((size_t)(bb * 16 + h) * 2048 + mloc + row) * 64) + off;
#pragma unroll
      for (int i4 = 0; i4 < 8; ++i4) {
        float4 t4 = make_float4(Cf[row * 65 + off + i4*4],     Cf[row * 65 + off + i4*4 + 1],
                                Cf[row * 65 + off + i4*4 + 2], Cf[row * 65 + off + i4*4 + 3]);
        *(float4*)(vp + i4 * 4) = t4;
      }
    }
  }
#undef STAGE
#undef COMPUTE
}

extern "C" void kernel_launch(void* const* d_in, const int* in_sizes, int n_in,
                              void* d_out, int out_size, void* d_ws, size_t ws_size,
                              hipStream_t stream) {
  const float* inp   = (const float*)d_in[0];
  const float* gamma = (const float*)d_in[1];
  const float* beta  = (const float*)d_in[2];
  const float* Wqk   = (const float*)d_in[3];
  const float* bqk   = (const float*)d_in[4];
  const float* Wv    = (const float*)d_in[5];
  const float* bv    = (const float*)d_in[6];
  float* out = (float*)d_out;

  unsigned short* X  = (unsigned short*)d_ws;             // 16384*1024 bf16 = 32 MB
  unsigned short* Wt = X + (size_t)M_TOT * D_DIM;         // 3072*1024 bf16  = 6 MB

  ln_kernel<<<M_TOT, 256, 0, stream>>>(inp, gamma, beta, X);
  wt_kernel<<<dim3(N_TOT / 64, D_DIM / 64), 256, 0, stream>>>(Wqk, Wv, Wt);
  gemm_kernel<<<(M_TOT / 128) * (N_TOT / 128), 256, 0, stream>>>(X, Wt, bqk, bv, out);
}

// Round 6
// 400.648 us; speedup vs baseline: 1.1030x; 1.0338x over previous
//
#include <hip/hip_runtime.h>
#include <hip/hip_bf16.h>

// Problem constants: B=8, NE=2048, D=1024, HEADS=16, hd=64
#define D_DIM 1024
#define M_TOT 16384      // B*NE
#define N_TOT 3072       // 2*D (qk) + D (v)
#define NQK   2048
#define QKV_SZ 16777216  // 8*16*2048*64

typedef __attribute__((ext_vector_type(8))) __bf16 bf16x8;
typedef __attribute__((ext_vector_type(4))) float floatx4;

__device__ __forceinline__ unsigned short f2bf(float f) {
  unsigned int u = __float_as_uint(f);
  u += 0x7FFFu + ((u >> 16) & 1u);   // round-to-nearest-even
  return (unsigned short)(u >> 16);
}

__device__ __forceinline__ void gl2lds16(const void* g, void* l) {
  // 16B per lane; LDS dest = wave-uniform base + lane*16 (HW-applied)
  __builtin_amdgcn_global_load_lds(
      (const __attribute__((address_space(1))) void*)g,
      (__attribute__((address_space(3))) void*)l, 16, 0, 0);
}

// ---------------- 1) LayerNorm + cast to bf16 ----------------
__global__ __launch_bounds__(256) void ln_kernel(
    const float* __restrict__ inp, const float* __restrict__ gamma,
    const float* __restrict__ beta, unsigned short* __restrict__ X) {
  const int row = blockIdx.x;
  const int t = threadIdx.x;
  const float* rp = inp + (size_t)row * D_DIM;
  float4 v = *(const float4*)(rp + t * 4);
  float s  = v.x + v.y + v.z + v.w;
  float s2 = v.x * v.x + v.y * v.y + v.z * v.z + v.w * v.w;
#pragma unroll
  for (int o = 1; o < 64; o <<= 1) {
    s  += __shfl_xor(s, o);
    s2 += __shfl_xor(s2, o);
  }
  __shared__ float ws[8];
  const int w = t >> 6, l = t & 63;
  if (l == 0) { ws[w] = s; ws[4 + w] = s2; }
  __syncthreads();
  s  = ws[0] + ws[1] + ws[2] + ws[3];
  s2 = ws[4] + ws[5] + ws[6] + ws[7];
  const float mu = s * (1.0f / D_DIM);
  const float var = s2 * (1.0f / D_DIM) - mu * mu;
  const float rstd = rsqrtf(var + 1e-5f);
  float4 g = *(const float4*)(gamma + t * 4);
  float4 b = *(const float4*)(beta + t * 4);
  ushort4 o;
  o.x = f2bf((v.x - mu) * rstd * g.x + b.x);
  o.y = f2bf((v.y - mu) * rstd * g.y + b.y);
  o.z = f2bf((v.z - mu) * rstd * g.z + b.z);
  o.w = f2bf((v.w - mu) * rstd * g.w + b.w);
  *(ushort4*)(X + (size_t)row * D_DIM + t * 4) = o;
}

// ---------------- 2) Weight transpose + cast: Wt[n][k] = W[k][n] ----------------
__global__ __launch_bounds__(256) void wt_kernel(
    const float* __restrict__ Wqk, const float* __restrict__ Wv,
    unsigned short* __restrict__ Wt) {
  __shared__ float tile[64][65];
  const int n0 = blockIdx.x * 64;
  const int k0 = blockIdx.y * 64;
  const float* src;
  int ldn, nc0;
  if (n0 < NQK) { src = Wqk; ldn = NQK; nc0 = n0; }
  else          { src = Wv;  ldn = D_DIM; nc0 = n0 - NQK; }
  const int t = threadIdx.x;
  const int r = t >> 4;            // 0..15
  const int c4 = (t & 15) << 2;    // 0..60
#pragma unroll
  for (int p = 0; p < 4; ++p) {
    int kk = p * 16 + r;
    float4 vv = *(const float4*)(src + (size_t)(k0 + kk) * ldn + nc0 + c4);
    tile[kk][c4 + 0] = vv.x;
    tile[kk][c4 + 1] = vv.y;
    tile[kk][c4 + 2] = vv.z;
    tile[kk][c4 + 3] = vv.w;
  }
  __syncthreads();
#pragma unroll
  for (int p = 0; p < 4; ++p) {
    int nn = p * 16 + r;
    ushort4 o;
    o.x = f2bf(tile[c4 + 0][nn]);
    o.y = f2bf(tile[c4 + 1][nn]);
    o.z = f2bf(tile[c4 + 2][nn]);
    o.w = f2bf(tile[c4 + 3][nn]);
    *(ushort4*)(Wt + (size_t)(n0 + nn) * D_DIM + k0 + c4) = o;
  }
}

// ---------------- 3) GEMM + bias + qkv scatter ----------------
// C[16384,3072] = X @ Wt^T ; 256x256 tile, BK=32, 8 waves (2Mx4N).
// 4-deep LDS ring (32KB each), counted s_waitcnt vmcnt(8) across raw barriers
// (never drains in-loop), XOR-swizzled LDS (both-sides involution), setprio
// around the MFMA cluster, XCD-chunked block swizzle.
__global__ __launch_bounds__(512, 2) void gemm_kernel(
    const unsigned short* __restrict__ X,    // [16384][1024] bf16
    const unsigned short* __restrict__ Wt,   // [3072][1024] bf16
    const float* __restrict__ bqk, const float* __restrict__ bv,
    float* __restrict__ out) {
  // 4 buffers x (A[256][32] 16KB + B[256][32] 16KB) = 128KB.
  // Epilogue aliases [0, 256*66*4=67584) as float Cf[256][66].
  __shared__ __align__(16) unsigned char smem[131072];

  // XCD-aware bijective swizzle: 768 blocks = 8 XCDs x 96.
  const int bid = blockIdx.x;
  const int xcd = bid & 7, tt = bid >> 3;        // tt in 0..95
  const int bm = xcd * 8 + tt / 12;              // 0..63
  const int bn = tt % 12;                        // 0..11
  const int m0 = bm * 256, n0 = bn * 256;

  const int tid = threadIdx.x;
  const int w = tid >> 6, l = tid & 63;
  const int wm = w >> 2, wn = w & 3;             // 2x4 wave grid
  const int lr = l & 15, lg = l >> 4;

  // Staging lane constants. Linear LDS slot (per call of 8KB):
  //   slot = w*1024 + l*16  -> row = w*16 + (l>>2), granule = l&3
  // Pre-swizzled global source: granule' = (l&3) ^ ((l>>3)&3)  (involution
  // partner of read-side off ^= ((off>>7)&3)<<4; row bits unchanged).
  const int rowL = w * 16 + (l >> 2);            // 0..127
  const int gcol = ((l & 3) ^ ((l >> 3) & 3)) * 8;  // elem offset 0/8/16/24
  const unsigned short* gA = X  + (size_t)(m0 + rowL) * D_DIM + gcol;
  const unsigned short* gB = Wt + (size_t)(n0 + rowL) * D_DIM + gcol;
  const int ldsW = w * 1024;                     // wave-uniform base

  floatx4 acc[8][4];
#pragma unroll
  for (int i = 0; i < 8; ++i)
#pragma unroll
    for (int j = 0; j < 4; ++j) acc[i][j] = (floatx4){0.f, 0.f, 0.f, 0.f};

  // STAGE one K-step (A 16KB + B 16KB) into ring buffer `buf`: 4 gload_lds/wave
#define STAGE(buf, ktn)                                                       \
  {                                                                           \
    const int kc_ = (ktn) * 32;                                               \
    unsigned char* base_ = smem + (buf) * 32768;                              \
    gl2lds16(gA + kc_,                       base_ + ldsW);                   \
    gl2lds16(gA + (size_t)128 * D_DIM + kc_, base_ + 8192 + ldsW);            \
    gl2lds16(gB + kc_,                       base_ + 16384 + ldsW);           \
    gl2lds16(gB + (size_t)128 * D_DIM + kc_, base_ + 24576 + ldsW);           \
  }

  // Prologue: fill 3 buffers (12 loads in flight).
  STAGE(0, 0);
  STAGE(1, 1);
  STAGE(2, 2);

#pragma unroll 1
  for (int kt = 0; kt < 32; ++kt) {
    // Counted wait: keep 8 loads (= stages t+1, t+2) in flight; stage(t) landed.
    asm volatile("s_waitcnt vmcnt(8)" ::: "memory");
    __builtin_amdgcn_s_barrier();

    const unsigned char* Ab = smem + (kt & 3) * 32768;
    const unsigned char* Bb = Ab + 16384;

    bf16x8 bfr[4];
#pragma unroll
    for (int ni = 0; ni < 4; ++ni) {
      int off = (wn * 64 + ni * 16 + lr) * 64 + lg * 16;
      off ^= ((off >> 7) & 3) << 4;            // bank swizzle (matches source)
      bfr[ni] = *(const bf16x8*)(Bb + off);
    }
    bf16x8 afr[8];
#pragma unroll
    for (int mi = 0; mi < 8; ++mi) {
      int off = (wm * 128 + mi * 16 + lr) * 64 + lg * 16;
      off ^= ((off >> 7) & 3) << 4;
      afr[mi] = *(const bf16x8*)(Ab + off);
    }

    // Stage 3 ahead into buf (kt+3)%4 — provably untouched this window.
    // Tail wraps to dummy re-stages (kept for uniform vmcnt accounting).
    STAGE((kt + 3) & 3, (kt + 3) & 31);

    __builtin_amdgcn_s_setprio(1);
#pragma unroll
    for (int mi = 0; mi < 8; ++mi)
#pragma unroll
      for (int ni = 0; ni < 4; ++ni)
        acc[mi][ni] = __builtin_amdgcn_mfma_f32_16x16x32_bf16(afr[mi], bfr[ni], acc[mi][ni], 0, 0, 0);
    __builtin_amdgcn_s_setprio(0);
  }
  // Drain dummy stages before reusing smem as Cf.
  asm volatile("s_waitcnt vmcnt(0)" ::: "memory");

  // ---- epilogue: 4 passes of 64 cols through LDS, coalesced float4 stores ----
  const size_t OQ = 0, OK = QKV_SZ, OV = 2 * (size_t)QKV_SZ;
  const int bb = m0 >> 11;          // batch (256 | 2048: tile within one batch)
  const int mloc = m0 & 2047;       // ne base
  float* Cf = (float*)smem;         // [256][66]

#pragma unroll 1
  for (int pass = 0; pass < 4; ++pass) {
    __syncthreads();
    if (wn == pass) {               // waves wm=0,1 of this wn own these 64 cols
#pragma unroll
      for (int ni = 0; ni < 4; ++ni) {
        const int cl = ni * 16 + lr;
        const int ng = n0 + pass * 64 + cl;
        const float bias = (ng < NQK) ? bqk[ng] : bv[ng - NQK];
#pragma unroll
        for (int mi = 0; mi < 8; ++mi) {
          const int r0 = wm * 128 + mi * 16 + lg * 4;
#pragma unroll
          for (int j = 0; j < 4; ++j)
            Cf[(r0 + j) * 66 + cl] = acc[mi][ni][j] + bias;
        }
      }
    }
    __syncthreads();
    const int ng0 = n0 + pass * 64;
    if (ng0 < NQK) {
      const int h = ng0 >> 7;              // 64-col pass sits in one head
      const int d0p = (ng0 & 127) >> 1;    // 0 or 32
      {
        // q[b][h][ne][d]: 256 rows x 32 d; thread: row=tid>>1, 16 d each
        const int row = tid >> 1, doff = (tid & 1) * 16;
        float* qp = out + OQ + (((size_t)(bb * 16 + h) * 2048 + mloc + row) * 64) + d0p + doff;
        float vb[16];
#pragma unroll
        for (int i = 0; i < 16; ++i) vb[i] = Cf[row * 66 + 2 * (doff + i)];
#pragma unroll
        for (int i4 = 0; i4 < 4; ++i4)
          *(float4*)(qp + i4 * 4) = make_float4(vb[i4*4], vb[i4*4+1], vb[i4*4+2], vb[i4*4+3]);
      }
      {
        // k[b][h][d][ne]: 32 d x 256 ne; thread: d=tid>>4, 16 ne each
        const int dl = tid >> 4;           // 0..31
        const int neo = (tid & 15) * 16;
        float* kp = out + OK + (((size_t)(bb * 16 + h) * 64 + d0p + dl) * 2048) + mloc + neo;
        float vb[16];
#pragma unroll
        for (int i = 0; i < 16; ++i) vb[i] = Cf[(neo + i) * 66 + 2 * dl + 1];
#pragma unroll
        for (int i4 = 0; i4 < 4; ++i4)
          *(float4*)(kp + i4 * 4) = make_float4(vb[i4*4], vb[i4*4+1], vb[i4*4+2], vb[i4*4+3]);
      }
    } else {
      // v[b][h][ne][d]: 64-col pass = exactly one v head
      const int vbase = ng0 - NQK;
      const int h = vbase >> 6;
      const int row = tid >> 1, off = (tid & 1) * 32;
      float* vp = out + OV + (((size_t)(bb * 16 + h) * 2048 + mloc + row) * 64) + off;
#pragma unroll
      for (int i4 = 0; i4 < 8; ++i4) {
        float4 t4 = make_float4(Cf[row * 66 + off + i4*4],     Cf[row * 66 + off + i4*4 + 1],
                                Cf[row * 66 + off + i4*4 + 2], Cf[row * 66 + off + i4*4 + 3]);
        *(float4*)(vp + i4 * 4) = t4;
      }
    }
  }
#undef STAGE
}

extern "C" void kernel_launch(void* const* d_in, const int* in_sizes, int n_in,
                              void* d_out, int out_size, void* d_ws, size_t ws_size,
                              hipStream_t stream) {
  const float* inp   = (const float*)d_in[0];
  const float* gamma = (const float*)d_in[1];
  const float* beta  = (const float*)d_in[2];
  const float* Wqk   = (const float*)d_in[3];
  const float* bqk   = (const float*)d_in[4];
  const float* Wv    = (const float*)d_in[5];
  const float* bv    = (const float*)d_in[6];
  float* out = (float*)d_out;

  unsigned short* X  = (unsigned short*)d_ws;             // 16384*1024 bf16 = 32 MB
  unsigned short* Wt = X + (size_t)M_TOT * D_DIM;         // 3072*1024 bf16  = 6 MB

  ln_kernel<<<M_TOT, 256, 0, stream>>>(inp, gamma, beta, X);
  wt_kernel<<<dim3(N_TOT / 64, D_DIM / 64), 256, 0, stream>>>(Wqk, Wv, Wt);
  gemm_kernel<<<(M_TOT / 256) * (N_TOT / 256), 512, 0, stream>>>(X, Wt, bqk, bv, out);
}

// Round 7
// 392.698 us; speedup vs baseline: 1.1254x; 1.0202x over previous
//
#include <hip/hip_runtime.h>
#include <hip/hip_bf16.h>

// Problem constants: B=8, NE=2048, D=1024, HEADS=16, hd=64
#define D_DIM 1024
#define M_TOT 16384      // B*NE
#define N_TOT 3072       // 2*D (qk) + D (v)
#define NQK   2048
#define QKV_SZ 16777216  // 8*16*2048*64

typedef __attribute__((ext_vector_type(8))) __bf16 bf16x8;
typedef __attribute__((ext_vector_type(4))) float floatx4;

__device__ __forceinline__ unsigned short f2bf(float f) {
  unsigned int u = __float_as_uint(f);
  u += 0x7FFFu + ((u >> 16) & 1u);   // round-to-nearest-even
  return (unsigned short)(u >> 16);
}

__device__ __forceinline__ void gl2lds16(const void* g, void* l) {
  // 16B per lane; LDS dest = wave-uniform base + lane*16 (HW-applied)
  __builtin_amdgcn_global_load_lds(
      (const __attribute__((address_space(1))) void*)g,
      (__attribute__((address_space(3))) void*)l, 16, 0, 0);
}

// ---------------- 1) LayerNorm + cast to bf16 ----------------
__global__ __launch_bounds__(256) void ln_kernel(
    const float* __restrict__ inp, const float* __restrict__ gamma,
    const float* __restrict__ beta, unsigned short* __restrict__ X) {
  const int row = blockIdx.x;
  const int t = threadIdx.x;
  const float* rp = inp + (size_t)row * D_DIM;
  float4 v = *(const float4*)(rp + t * 4);
  float s  = v.x + v.y + v.z + v.w;
  float s2 = v.x * v.x + v.y * v.y + v.z * v.z + v.w * v.w;
#pragma unroll
  for (int o = 1; o < 64; o <<= 1) {
    s  += __shfl_xor(s, o);
    s2 += __shfl_xor(s2, o);
  }
  __shared__ float ws[8];
  const int w = t >> 6, l = t & 63;
  if (l == 0) { ws[w] = s; ws[4 + w] = s2; }
  __syncthreads();
  s  = ws[0] + ws[1] + ws[2] + ws[3];
  s2 = ws[4] + ws[5] + ws[6] + ws[7];
  const float mu = s * (1.0f / D_DIM);
  const float var = s2 * (1.0f / D_DIM) - mu * mu;
  const float rstd = rsqrtf(var + 1e-5f);
  float4 g = *(const float4*)(gamma + t * 4);
  float4 b = *(const float4*)(beta + t * 4);
  ushort4 o;
  o.x = f2bf((v.x - mu) * rstd * g.x + b.x);
  o.y = f2bf((v.y - mu) * rstd * g.y + b.y);
  o.z = f2bf((v.z - mu) * rstd * g.z + b.z);
  o.w = f2bf((v.w - mu) * rstd * g.w + b.w);
  *(ushort4*)(X + (size_t)row * D_DIM + t * 4) = o;
}

// ---------------- 2) Weight transpose + cast: Wt[n][k] = W[k][n] ----------------
__global__ __launch_bounds__(256) void wt_kernel(
    const float* __restrict__ Wqk, const float* __restrict__ Wv,
    unsigned short* __restrict__ Wt) {
  __shared__ float tile[64][65];
  const int n0 = blockIdx.x * 64;
  const int k0 = blockIdx.y * 64;
  const float* src;
  int ldn, nc0;
  if (n0 < NQK) { src = Wqk; ldn = NQK; nc0 = n0; }
  else          { src = Wv;  ldn = D_DIM; nc0 = n0 - NQK; }
  const int t = threadIdx.x;
  const int r = t >> 4;            // 0..15
  const int c4 = (t & 15) << 2;    // 0..60
#pragma unroll
  for (int p = 0; p < 4; ++p) {
    int kk = p * 16 + r;
    float4 vv = *(const float4*)(src + (size_t)(k0 + kk) * ldn + nc0 + c4);
    tile[kk][c4 + 0] = vv.x;
    tile[kk][c4 + 1] = vv.y;
    tile[kk][c4 + 2] = vv.z;
    tile[kk][c4 + 3] = vv.w;
  }
  __syncthreads();
#pragma unroll
  for (int p = 0; p < 4; ++p) {
    int nn = p * 16 + r;
    ushort4 o;
    o.x = f2bf(tile[c4 + 0][nn]);
    o.y = f2bf(tile[c4 + 1][nn]);
    o.z = f2bf(tile[c4 + 2][nn]);
    o.w = f2bf(tile[c4 + 3][nn]);
    *(ushort4*)(Wt + (size_t)(n0 + nn) * D_DIM + k0 + c4) = o;
  }
}

// ---------------- 3) GEMM + bias + qkv scatter ----------------
// C[16384,3072] = X @ Wt^T ; 256x256 tile, BK=32, 8 waves (2Mx4N).
// 4-deep LDS ring, counted vmcnt(8) (3-step staging slack), ONE barrier per
// K-step, phase-split compute (2 x {stage, ds_read burst, 16 MFMA}) so lgkm
// chains are short and waves self-stagger; setprio on MFMA clusters.
__global__ __launch_bounds__(512, 2) void gemm_kernel(
    const unsigned short* __restrict__ X,    // [16384][1024] bf16
    const unsigned short* __restrict__ Wt,   // [3072][1024] bf16
    const float* __restrict__ bqk, const float* __restrict__ bv,
    float* __restrict__ out) {
  // 4 buffers x (A[256][32] 16KB + B[256][32] 16KB) = 128KB.
  // Epilogue aliases [0, 256*66*4) as float Cf[256][66].
  __shared__ __align__(16) unsigned char smem[131072];

  // XCD-aware bijective swizzle: 768 blocks = 8 XCDs x 96.
  const int bid = blockIdx.x;
  const int xcd = bid & 7, tt = bid >> 3;        // tt in 0..95
  const int bm = xcd * 8 + tt / 12;              // 0..63
  const int bn = tt % 12;                        // 0..11
  const int m0 = bm * 256, n0 = bn * 256;

  const int tid = threadIdx.x;
  const int w = tid >> 6, l = tid & 63;
  const int wm = w >> 2, wn = w & 3;             // 2x4 wave grid
  const int lr = l & 15, lg = l >> 4;

  // Staging: linear LDS slot (8KB per call) = w*1024 + l*16
  //   -> row = w*16 + (l>>2), granule = l&3
  // Pre-swizzled global source granule' = (l&3)^((l>>3)&3), the involution
  // partner of read-side off ^= ((off>>7)&3)<<4 (conflict-free frag reads:
  // each 16-lane group spreads over all 8 bank-quads, 2 lanes each).
  const int rowL = w * 16 + (l >> 2);            // 0..127
  const int gcol = ((l & 3) ^ ((l >> 3) & 3)) * 8;
  const unsigned short* gA = X  + (size_t)(m0 + rowL) * D_DIM + gcol;
  const unsigned short* gB = Wt + (size_t)(n0 + rowL) * D_DIM + gcol;
  const int ldsW = w * 1024;                     // wave-uniform base

  floatx4 acc[8][4];
#pragma unroll
  for (int i = 0; i < 8; ++i)
#pragma unroll
    for (int j = 0; j < 4; ++j) acc[i][j] = (floatx4){0.f, 0.f, 0.f, 0.f};

  // Half-stages: A-part (2 loads) and B-part (2 loads) of one K-step tile.
#define STAGE_A(buf, ktn)                                                     \
  {                                                                           \
    const int kc_ = (ktn) * 32;                                               \
    unsigned char* base_ = smem + (buf) * 32768;                              \
    gl2lds16(gA + kc_,                       base_ + ldsW);                   \
    gl2lds16(gA + (size_t)128 * D_DIM + kc_, base_ + 8192 + ldsW);            \
  }
#define STAGE_B(buf, ktn)                                                     \
  {                                                                           \
    const int kc_ = (ktn) * 32;                                               \
    unsigned char* base_ = smem + (buf) * 32768;                              \
    gl2lds16(gB + kc_,                       base_ + 16384 + ldsW);           \
    gl2lds16(gB + (size_t)128 * D_DIM + kc_, base_ + 24576 + ldsW);           \
  }

  // Prologue: fill 3 buffers (12 loads in flight).
  STAGE_A(0, 0); STAGE_B(0, 0);
  STAGE_A(1, 1); STAGE_B(1, 1);
  STAGE_A(2, 2); STAGE_B(2, 2);

#pragma unroll 1
  for (int kt = 0; kt < 32; ++kt) {
    // Retire stage(kt) (its 4 loads are the oldest; issued 3 steps ago).
    asm volatile("s_waitcnt vmcnt(8)" ::: "memory");
    __builtin_amdgcn_s_barrier();

    const unsigned char* Ab = smem + (kt & 3) * 32768;
    const unsigned char* Bb = Ab + 16384;
    const int nbuf = (kt + 3) & 3, nkt = (kt + 3) & 31;

    // ---- phase 0: B frags + A lo-half ----
    STAGE_A(nbuf, nkt);
    bf16x8 bfr[4], afr[4];
#pragma unroll
    for (int ni = 0; ni < 4; ++ni) {
      int off = (wn * 64 + ni * 16 + lr) * 64 + lg * 16;
      off ^= ((off >> 7) & 3) << 4;
      bfr[ni] = *(const bf16x8*)(Bb + off);
    }
#pragma unroll
    for (int mi = 0; mi < 4; ++mi) {
      int off = (wm * 128 + mi * 16 + lr) * 64 + lg * 16;
      off ^= ((off >> 7) & 3) << 4;
      afr[mi] = *(const bf16x8*)(Ab + off);
    }
    __builtin_amdgcn_s_setprio(1);
#pragma unroll
    for (int mi = 0; mi < 4; ++mi)
#pragma unroll
      for (int ni = 0; ni < 4; ++ni)
        acc[mi][ni] = __builtin_amdgcn_mfma_f32_16x16x32_bf16(afr[mi], bfr[ni], acc[mi][ni], 0, 0, 0);
    __builtin_amdgcn_s_setprio(0);
    __builtin_amdgcn_sched_barrier(0);   // keep phase 1 reads below phase 0 MFMAs

    // ---- phase 1: A hi-half ----
    STAGE_B(nbuf, nkt);
    bf16x8 afr2[4];
#pragma unroll
    for (int mi = 0; mi < 4; ++mi) {
      int off = (wm * 128 + (mi + 4) * 16 + lr) * 64 + lg * 16;
      off ^= ((off >> 7) & 3) << 4;
      afr2[mi] = *(const bf16x8*)(Ab + off);
    }
    __builtin_amdgcn_s_setprio(1);
#pragma unroll
    for (int mi = 0; mi < 4; ++mi)
#pragma unroll
      for (int ni = 0; ni < 4; ++ni)
        acc[mi + 4][ni] = __builtin_amdgcn_mfma_f32_16x16x32_bf16(afr2[mi], bfr[ni], acc[mi + 4][ni], 0, 0, 0);
    __builtin_amdgcn_s_setprio(0);
  }
  // Drain dummy tail stages before reusing smem as Cf.
  asm volatile("s_waitcnt vmcnt(0)" ::: "memory");

  // ---- epilogue: 4 passes of 64 cols through LDS, coalesced float4 stores ----
  const size_t OQ = 0, OK = QKV_SZ, OV = 2 * (size_t)QKV_SZ;
  const int bb = m0 >> 11;          // batch (tile sits in one batch)
  const int mloc = m0 & 2047;       // ne base
  float* Cf = (float*)smem;         // [256][66]

#pragma unroll 1
  for (int pass = 0; pass < 4; ++pass) {
    __syncthreads();
    if (wn == pass) {               // waves wm=0,1 of this wn own these 64 cols
#pragma unroll
      for (int ni = 0; ni < 4; ++ni) {
        const int cl = ni * 16 + lr;
        const int ng = n0 + pass * 64 + cl;
        const float bias = (ng < NQK) ? bqk[ng] : bv[ng - NQK];
#pragma unroll
        for (int mi = 0; mi < 8; ++mi) {
          const int r0 = wm * 128 + mi * 16 + lg * 4;
#pragma unroll
          for (int j = 0; j < 4; ++j)
            Cf[(r0 + j) * 66 + cl] = acc[mi][ni][j] + bias;
        }
      }
    }
    __syncthreads();
    const int ng0 = n0 + pass * 64;
    if (ng0 < NQK) {
      const int h = ng0 >> 7;              // 64-col pass sits in one head
      const int d0p = (ng0 & 127) >> 1;    // 0 or 32
      {
        // q[b][h][ne][d]: 256 rows x 32 d; thread: row=tid>>1, 16 d each
        const int row = tid >> 1, doff = (tid & 1) * 16;
        float* qp = out + OQ + (((size_t)(bb * 16 + h) * 2048 + mloc + row) * 64) + d0p + doff;
        float vb[16];
#pragma unroll
        for (int i = 0; i < 16; ++i) vb[i] = Cf[row * 66 + 2 * (doff + i)];
#pragma unroll
        for (int i4 = 0; i4 < 4; ++i4)
          *(float4*)(qp + i4 * 4) = make_float4(vb[i4*4], vb[i4*4+1], vb[i4*4+2], vb[i4*4+3]);
      }
      {
        // k[b][h][d][ne]: 32 d x 256 ne. Bank-conflict-safe mapping:
        // thread: d = tid>>4, ne runs of 4 at ne = 4*(tid&15) + 64*g.
        // Lane bank term 8*l mod 32 -> 4-way (cheap); stores stay float4.
        const int dl = tid >> 4;           // 0..31
        const int L4 = (tid & 15) * 4;
        float* kp = out + OK + (((size_t)(bb * 16 + h) * 64 + d0p + dl) * 2048) + mloc;
#pragma unroll
        for (int g = 0; g < 4; ++g) {
          const int ne = L4 + 64 * g;
          float4 t4 = make_float4(Cf[(ne + 0) * 66 + 2 * dl + 1],
                                  Cf[(ne + 1) * 66 + 2 * dl + 1],
                                  Cf[(ne + 2) * 66 + 2 * dl + 1],
                                  Cf[(ne + 3) * 66 + 2 * dl + 1]);
          *(float4*)(kp + ne) = t4;
        }
      }
    } else {
      // v[b][h][ne][d]: 64-col pass = exactly one v head
      const int vbase = ng0 - NQK;
      const int h = vbase >> 6;
      const int row = tid >> 1, off = (tid & 1) * 32;
      float* vp = out + OV + (((size_t)(bb * 16 + h) * 2048 + mloc + row) * 64) + off;
#pragma unroll
      for (int i4 = 0; i4 < 8; ++i4) {
        float4 t4 = make_float4(Cf[row * 66 + off + i4*4],     Cf[row * 66 + off + i4*4 + 1],
                                Cf[row * 66 + off + i4*4 + 2], Cf[row * 66 + off + i4*4 + 3]);
        *(float4*)(vp + i4 * 4) = t4;
      }
    }
  }
#undef STAGE_A
#undef STAGE_B
}

extern "C" void kernel_launch(void* const* d_in, const int* in_sizes, int n_in,
                              void* d_out, int out_size, void* d_ws, size_t ws_size,
                              hipStream_t stream) {
  const float* inp   = (const float*)d_in[0];
  const float* gamma = (const float*)d_in[1];
  const float* beta  = (const float*)d_in[2];
  const float* Wqk   = (const float*)d_in[3];
  const float* bqk   = (const float*)d_in[4];
  const float* Wv    = (const float*)d_in[5];
  const float* bv    = (const float*)d_in[6];
  float* out = (float*)d_out;

  unsigned short* X  = (unsigned short*)d_ws;             // 16384*1024 bf16 = 32 MB
  unsigned short* Wt = X + (size_t)M_TOT * D_DIM;         // 3072*1024 bf16  = 6 MB

  ln_kernel<<<M_TOT, 256, 0, stream>>>(inp, gamma, beta, X);
  wt_kernel<<<dim3(N_TOT / 64, D_DIM / 64), 256, 0, stream>>>(Wqk, Wv, Wt);
  gemm_kernel<<<(M_TOT / 256) * (N_TOT / 256), 512, 0, stream>>>(X, Wt, bqk, bv, out);
}

// Round 8
// 392.096 us; speedup vs baseline: 1.1271x; 1.0015x over previous
//
#include <hip/hip_runtime.h>
#include <hip/hip_bf16.h>

// Problem constants: B=8, NE=2048, D=1024, HEADS=16, hd=64
#define D_DIM 1024
#define M_TOT 16384      // B*NE
#define N_TOT 3072       // 2*D (qk) + D (v)
#define NQK   2048
#define QKV_SZ 16777216  // 8*16*2048*64

typedef __attribute__((ext_vector_type(8))) __bf16 bf16x8;
typedef __attribute__((ext_vector_type(4))) float floatx4;

__device__ __forceinline__ unsigned short f2bf(float f) {
  unsigned int u = __float_as_uint(f);
  u += 0x7FFFu + ((u >> 16) & 1u);   // round-to-nearest-even
  return (unsigned short)(u >> 16);
}

__device__ __forceinline__ void gl2lds16(const void* g, void* l) {
  // 16B per lane; LDS dest = wave-uniform base + lane*16 (HW-applied)
  __builtin_amdgcn_global_load_lds(
      (const __attribute__((address_space(1))) void*)g,
      (__attribute__((address_space(3))) void*)l, 16, 0, 0);
}

// ---------------- 1) LayerNorm + cast to bf16 ----------------
__global__ __launch_bounds__(256) void ln_kernel(
    const float* __restrict__ inp, const float* __restrict__ gamma,
    const float* __restrict__ beta, unsigned short* __restrict__ X) {
  const int row = blockIdx.x;
  const int t = threadIdx.x;
  const float* rp = inp + (size_t)row * D_DIM;
  float4 v = *(const float4*)(rp + t * 4);
  float s  = v.x + v.y + v.z + v.w;
  float s2 = v.x * v.x + v.y * v.y + v.z * v.z + v.w * v.w;
#pragma unroll
  for (int o = 1; o < 64; o <<= 1) {
    s  += __shfl_xor(s, o);
    s2 += __shfl_xor(s2, o);
  }
  __shared__ float ws[8];
  const int w = t >> 6, l = t & 63;
  if (l == 0) { ws[w] = s; ws[4 + w] = s2; }
  __syncthreads();
  s  = ws[0] + ws[1] + ws[2] + ws[3];
  s2 = ws[4] + ws[5] + ws[6] + ws[7];
  const float mu = s * (1.0f / D_DIM);
  const float var = s2 * (1.0f / D_DIM) - mu * mu;
  const float rstd = rsqrtf(var + 1e-5f);
  float4 g = *(const float4*)(gamma + t * 4);
  float4 b = *(const float4*)(beta + t * 4);
  ushort4 o;
  o.x = f2bf((v.x - mu) * rstd * g.x + b.x);
  o.y = f2bf((v.y - mu) * rstd * g.y + b.y);
  o.z = f2bf((v.z - mu) * rstd * g.z + b.z);
  o.w = f2bf((v.w - mu) * rstd * g.w + b.w);
  *(ushort4*)(X + (size_t)row * D_DIM + t * 4) = o;
}

// ---------------- 2) Weight transpose + cast: Wt[n][k] = W[k][n] ----------------
__global__ __launch_bounds__(256) void wt_kernel(
    const float* __restrict__ Wqk, const float* __restrict__ Wv,
    unsigned short* __restrict__ Wt) {
  __shared__ float tile[64][65];
  const int n0 = blockIdx.x * 64;
  const int k0 = blockIdx.y * 64;
  const float* src;
  int ldn, nc0;
  if (n0 < NQK) { src = Wqk; ldn = NQK; nc0 = n0; }
  else          { src = Wv;  ldn = D_DIM; nc0 = n0 - NQK; }
  const int t = threadIdx.x;
  const int r = t >> 4;            // 0..15
  const int c4 = (t & 15) << 2;    // 0..60
#pragma unroll
  for (int p = 0; p < 4; ++p) {
    int kk = p * 16 + r;
    float4 vv = *(const float4*)(src + (size_t)(k0 + kk) * ldn + nc0 + c4);
    tile[kk][c4 + 0] = vv.x;
    tile[kk][c4 + 1] = vv.y;
    tile[kk][c4 + 2] = vv.z;
    tile[kk][c4 + 3] = vv.w;
  }
  __syncthreads();
#pragma unroll
  for (int p = 0; p < 4; ++p) {
    int nn = p * 16 + r;
    ushort4 o;
    o.x = f2bf(tile[c4 + 0][nn]);
    o.y = f2bf(tile[c4 + 1][nn]);
    o.z = f2bf(tile[c4 + 2][nn]);
    o.w = f2bf(tile[c4 + 3][nn]);
    *(ushort4*)(Wt + (size_t)(n0 + nn) * D_DIM + k0 + c4) = o;
  }
}

// ---------------- 3) GEMM + bias + qkv scatter ----------------
// C[16384,3072] = X @ Wt^T ; 256x256 tile, BK=32, 8 waves (2Mx4N).
// 4-deep LDS ring, counted vmcnt(8); K-step split into TWO template-style
// phases, each {mem region (ds_read burst + stage issue) -> s_barrier ->
// 16-MFMA cluster -> s_barrier}, pinned at boundaries with sched_barrier(0).
__global__ __launch_bounds__(512, 2) void gemm_kernel(
    const unsigned short* __restrict__ X,    // [16384][1024] bf16
    const unsigned short* __restrict__ Wt,   // [3072][1024] bf16
    const float* __restrict__ bqk, const float* __restrict__ bv,
    float* __restrict__ out) {
  // 4 buffers x (A[256][32] 16KB + B[256][32] 16KB) = 128KB.
  // Epilogue aliases [0, 256*66*4) as float Cf[256][66].
  __shared__ __align__(16) unsigned char smem[131072];

  // XCD-aware bijective swizzle: 768 blocks = 8 XCDs x 96.
  const int bid = blockIdx.x;
  const int xcd = bid & 7, tt = bid >> 3;        // tt in 0..95
  const int bm = xcd * 8 + tt / 12;              // 0..63
  const int bn = tt % 12;                        // 0..11
  const int m0 = bm * 256, n0 = bn * 256;

  const int tid = threadIdx.x;
  const int w = tid >> 6, l = tid & 63;
  const int wm = w >> 2, wn = w & 3;             // 2x4 wave grid
  const int lr = l & 15, lg = l >> 4;

  // Staging: linear LDS slot (8KB per call) = w*1024 + l*16
  //   -> row = w*16 + (l>>2), granule = l&3
  // Pre-swizzled global source granule' = (l&3)^((l>>3)&3), involution
  // partner of read-side off ^= ((off>>7)&3)<<4.
  const int rowL = w * 16 + (l >> 2);            // 0..127
  const int gcol = ((l & 3) ^ ((l >> 3) & 3)) * 8;
  const unsigned short* gA = X  + (size_t)(m0 + rowL) * D_DIM + gcol;
  const unsigned short* gB = Wt + (size_t)(n0 + rowL) * D_DIM + gcol;
  const int ldsW = w * 1024;                     // wave-uniform base

  floatx4 acc[8][4];
#pragma unroll
  for (int i = 0; i < 8; ++i)
#pragma unroll
    for (int j = 0; j < 4; ++j) acc[i][j] = (floatx4){0.f, 0.f, 0.f, 0.f};

#define STAGE_A(buf, ktn)                                                     \
  {                                                                           \
    const int kc_ = (ktn) * 32;                                               \
    unsigned char* base_ = smem + (buf) * 32768;                              \
    gl2lds16(gA + kc_,                       base_ + ldsW);                   \
    gl2lds16(gA + (size_t)128 * D_DIM + kc_, base_ + 8192 + ldsW);            \
  }
#define STAGE_B(buf, ktn)                                                     \
  {                                                                           \
    const int kc_ = (ktn) * 32;                                               \
    unsigned char* base_ = smem + (buf) * 32768;                              \
    gl2lds16(gB + kc_,                       base_ + 16384 + ldsW);           \
    gl2lds16(gB + (size_t)128 * D_DIM + kc_, base_ + 24576 + ldsW);           \
  }

  // Prologue: fill 3 buffers (12 loads in flight).
  STAGE_A(0, 0); STAGE_B(0, 0);
  STAGE_A(1, 1); STAGE_B(1, 1);
  STAGE_A(2, 2); STAGE_B(2, 2);

#pragma unroll 1
  for (int kt = 0; kt < 32; ++kt) {
    // Retire stage(kt): its 4 loads are the oldest (issued 3 steps ago).
    asm volatile("s_waitcnt vmcnt(8)" ::: "memory");
    __builtin_amdgcn_s_barrier();              // open: buf kt valid for all
    __builtin_amdgcn_sched_barrier(0);

    const unsigned char* Ab = smem + (kt & 3) * 32768;
    const unsigned char* Bb = Ab + 16384;
    const int nbuf = (kt + 3) & 3, nkt = (kt + 3) & 31;

    // ===== phase 0: mem {B frags, A-lo frags, STAGE_A(kt+3)} =====
    bf16x8 bfr[4], afr[4];
#pragma unroll
    for (int ni = 0; ni < 4; ++ni) {
      int off = (wn * 64 + ni * 16 + lr) * 64 + lg * 16;
      off ^= ((off >> 7) & 3) << 4;
      bfr[ni] = *(const bf16x8*)(Bb + off);
    }
#pragma unroll
    for (int mi = 0; mi < 4; ++mi) {
      int off = (wm * 128 + mi * 16 + lr) * 64 + lg * 16;
      off ^= ((off >> 7) & 3) << 4;
      afr[mi] = *(const bf16x8*)(Ab + off);
    }
    STAGE_A(nbuf, nkt);
    __builtin_amdgcn_sched_barrier(0);
    __builtin_amdgcn_s_barrier();              // phase-0 compute gate
    __builtin_amdgcn_sched_barrier(0);
    __builtin_amdgcn_s_setprio(1);
#pragma unroll
    for (int mi = 0; mi < 4; ++mi)
#pragma unroll
      for (int ni = 0; ni < 4; ++ni)
        acc[mi][ni] = __builtin_amdgcn_mfma_f32_16x16x32_bf16(afr[mi], bfr[ni], acc[mi][ni], 0, 0, 0);
    __builtin_amdgcn_s_setprio(0);
    __builtin_amdgcn_sched_barrier(0);
    __builtin_amdgcn_s_barrier();              // phase-0 close
    __builtin_amdgcn_sched_barrier(0);

    // ===== phase 1: mem {A-hi frags, STAGE_B(kt+3)} =====
    bf16x8 afr2[4];
#pragma unroll
    for (int mi = 0; mi < 4; ++mi) {
      int off = (wm * 128 + (mi + 4) * 16 + lr) * 64 + lg * 16;
      off ^= ((off >> 7) & 3) << 4;
      afr2[mi] = *(const bf16x8*)(Ab + off);
    }
    STAGE_B(nbuf, nkt);
    __builtin_amdgcn_sched_barrier(0);
    __builtin_amdgcn_s_barrier();              // phase-1 compute gate
    __builtin_amdgcn_sched_barrier(0);
    __builtin_amdgcn_s_setprio(1);
#pragma unroll
    for (int mi = 0; mi < 4; ++mi)
#pragma unroll
      for (int ni = 0; ni < 4; ++ni)
        acc[mi + 4][ni] = __builtin_amdgcn_mfma_f32_16x16x32_bf16(afr2[mi], bfr[ni], acc[mi + 4][ni], 0, 0, 0);
    __builtin_amdgcn_s_setprio(0);
    __builtin_amdgcn_sched_barrier(0);
    // phase-1 close = next iteration's open barrier
  }
  // Drain dummy tail stages before reusing smem as Cf.
  asm volatile("s_waitcnt vmcnt(0)" ::: "memory");

  // ---- epilogue: 4 passes of 64 cols through LDS, coalesced float4 stores ----
  const size_t OQ = 0, OK = QKV_SZ, OV = 2 * (size_t)QKV_SZ;
  const int bb = m0 >> 11;          // batch (tile sits in one batch)
  const int mloc = m0 & 2047;       // ne base
  float* Cf = (float*)smem;         // [256][66]

#pragma unroll 1
  for (int pass = 0; pass < 4; ++pass) {
    __syncthreads();
    if (wn == pass) {               // waves wm=0,1 of this wn own these 64 cols
#pragma unroll
      for (int ni = 0; ni < 4; ++ni) {
        const int cl = ni * 16 + lr;
        const int ng = n0 + pass * 64 + cl;
        const float bias = (ng < NQK) ? bqk[ng] : bv[ng - NQK];
#pragma unroll
        for (int mi = 0; mi < 8; ++mi) {
          const int r0 = wm * 128 + mi * 16 + lg * 4;
#pragma unroll
          for (int j = 0; j < 4; ++j)
            Cf[(r0 + j) * 66 + cl] = acc[mi][ni][j] + bias;
        }
      }
    }
    __syncthreads();
    const int ng0 = n0 + pass * 64;
    if (ng0 < NQK) {
      const int h = ng0 >> 7;              // 64-col pass sits in one head
      const int d0p = (ng0 & 127) >> 1;    // 0 or 32
      {
        // q[b][h][ne][d]: 256 rows x 32 d; thread: row=tid>>1, 16 d each
        const int row = tid >> 1, doff = (tid & 1) * 16;
        float* qp = out + OQ + (((size_t)(bb * 16 + h) * 2048 + mloc + row) * 64) + d0p + doff;
        float vb[16];
#pragma unroll
        for (int i = 0; i < 16; ++i) vb[i] = Cf[row * 66 + 2 * (doff + i)];
#pragma unroll
        for (int i4 = 0; i4 < 4; ++i4)
          *(float4*)(qp + i4 * 4) = make_float4(vb[i4*4], vb[i4*4+1], vb[i4*4+2], vb[i4*4+3]);
      }
      {
        // k[b][h][d][ne]: thread d = tid>>4, ne runs of 4 at ne = 4*(tid&15)+64g
        // (lane bank term 8*l mod 32 -> 4-way, cheap; stores stay float4)
        const int dl = tid >> 4;           // 0..31
        const int L4 = (tid & 15) * 4;
        float* kp = out + OK + (((size_t)(bb * 16 + h) * 64 + d0p + dl) * 2048) + mloc;
#pragma unroll
        for (int g = 0; g < 4; ++g) {
          const int ne = L4 + 64 * g;
          float4 t4 = make_float4(Cf[(ne + 0) * 66 + 2 * dl + 1],
                                  Cf[(ne + 1) * 66 + 2 * dl + 1],
                                  Cf[(ne + 2) * 66 + 2 * dl + 1],
                                  Cf[(ne + 3) * 66 + 2 * dl + 1]);
          *(float4*)(kp + ne) = t4;
        }
      }
    } else {
      // v[b][h][ne][d]: 64-col pass = exactly one v head
      const int vbase = ng0 - NQK;
      const int h = vbase >> 6;
      const int row = tid >> 1, off = (tid & 1) * 32;
      float* vp = out + OV + (((size_t)(bb * 16 + h) * 2048 + mloc + row) * 64) + off;
#pragma unroll
      for (int i4 = 0; i4 < 8; ++i4) {
        float4 t4 = make_float4(Cf[row * 66 + off + i4*4],     Cf[row * 66 + off + i4*4 + 1],
                                Cf[row * 66 + off + i4*4 + 2], Cf[row * 66 + off + i4*4 + 3]);
        *(float4*)(vp + i4 * 4) = t4;
      }
    }
  }
#undef STAGE_A
#undef STAGE_B
}

extern "C" void kernel_launch(void* const* d_in, const int* in_sizes, int n_in,
                              void* d_out, int out_size, void* d_ws, size_t ws_size,
                              hipStream_t stream) {
  const float* inp   = (const float*)d_in[0];
  const float* gamma = (const float*)d_in[1];
  const float* beta  = (const float*)d_in[2];
  const float* Wqk   = (const float*)d_in[3];
  const float* bqk   = (const float*)d_in[4];
  const float* Wv    = (const float*)d_in[5];
  const float* bv    = (const float*)d_in[6];
  float* out = (float*)d_out;

  unsigned short* X  = (unsigned short*)d_ws;             // 16384*1024 bf16 = 32 MB
  unsigned short* Wt = X + (size_t)M_TOT * D_DIM;         // 3072*1024 bf16  = 6 MB

  ln_kernel<<<M_TOT, 256, 0, stream>>>(inp, gamma, beta, X);
  wt_kernel<<<dim3(N_TOT / 64, D_DIM / 64), 256, 0, stream>>>(Wqk, Wv, Wt);
  gemm_kernel<<<(M_TOT / 256) * (N_TOT / 256), 512, 0, stream>>>(X, Wt, bqk, bv, out);
}